// Round 1
// baseline (144.002 us; speedup 1.0000x reference)
//
#include <hip/hip_runtime.h>
#include <math.h>

#define BATCH  4
#define SEQL   4096
#define DMODEL 1024
#define NSTATE 64
#define LN_EPS 1e-5f
#define TB     32   // time sub-block held in registers

// ---------------------------------------------------------------------------
// Pass 1: per-(b, d, chunk) local scan with zero init; writes local final
// states f[b][j][n][d] (layout chosen so all passes get coalesced d-fastest).
// ---------------------------------------------------------------------------
__global__ __launch_bounds__(256) void k_pass1(const float* __restrict__ u,
                                               const float* __restrict__ A_log,
                                               const float* __restrict__ delta,
                                               float* __restrict__ f,
                                               int NCH, int T) {
    __shared__ float r_lds[NSTATE];
    const int tid = threadIdx.x;
    const int wave = tid >> 6, lane = tid & 63;
    if (tid < NSTATE) {
        float A = -expf(A_log[tid]);
        r_lds[tid] = expf(delta[0] * A);
    }
    __syncthreads();

    const int cpb = NCH >> 2;                 // chunk-groups per (b, d-tile)
    const int b   = blockIdx.x / (16 * cpb);
    const int rem = blockIdx.x % (16 * cpb);
    const int dt  = rem / cpb;
    const int jg  = rem % cpb;
    const int j   = (jg << 2) | wave;
    const int d   = (dt << 6) | lane;

    float s[NSTATE];
#pragma unroll
    for (int n = 0; n < NSTATE; ++n) s[n] = 0.f;

    const float* ub = u + ((size_t)b * SEQL + (size_t)j * T) * DMODEL + d;
    const int ntb = T / TB;
    for (int tb = 0; tb < ntb; ++tb) {
        float ur[TB];
#pragma unroll
        for (int t = 0; t < TB; ++t)
            ur[t] = ub[(size_t)(tb * TB + t) * DMODEL];
#pragma unroll
        for (int n = 0; n < NSTATE; ++n) {
            const float rn = r_lds[n];
            float sn = s[n];
#pragma unroll
            for (int t = 0; t < TB; ++t) sn = fmaf(rn, sn, ur[t]);
            s[n] = sn;
        }
    }
    float* fb = f + (((size_t)b * NCH + j) * NSTATE) * DMODEL + d;
#pragma unroll
    for (int n = 0; n < NSTATE; ++n) fb[(size_t)n * DMODEL] = s[n];
}

// ---------------------------------------------------------------------------
// Pass 2: in-place scan over chunk boundaries. f[b][j][n][d] becomes
// I[b][j][n][d] = global state entering chunk j. One thread per (b,n,d).
// ---------------------------------------------------------------------------
__global__ __launch_bounds__(256) void k_pass2(const float* __restrict__ A_log,
                                               const float* __restrict__ delta,
                                               float* __restrict__ f,
                                               int NCH, int T) {
    const int tid = blockIdx.x * 256 + threadIdx.x;  // over B*N*D
    const int d = tid & (DMODEL - 1);
    const int n = (tid >> 10) & (NSTATE - 1);
    const int b = tid >> 16;
    const float A  = -expf(A_log[n]);
    const float rT = expf((float)T * delta[0] * A);
    float I = 0.f;
    float* p = f + ((size_t)b * NCH * NSTATE + n) * DMODEL + d;
    const size_t stride = (size_t)NSTATE * DMODEL;
    for (int j = 0; j < NCH; ++j) {
        float tmp = p[(size_t)j * stride];
        p[(size_t)j * stride] = I;
        I = fmaf(rT, I, tmp);
    }
}

// ---------------------------------------------------------------------------
// Pass 3: replay each chunk with its correct initial state; emit
// y_pre = conv(u,K) + u*D  into d_out's y region.
// ---------------------------------------------------------------------------
__global__ __launch_bounds__(256) void k_pass3(const float* __restrict__ u,
                                               const float* __restrict__ A_log,
                                               const float* __restrict__ C,
                                               const float* __restrict__ Dvec,
                                               const float* __restrict__ delta,
                                               const float* __restrict__ I,
                                               float* __restrict__ y,
                                               int NCH, int T) {
    __shared__ float r_lds[NSTATE];
    __shared__ float c_lds[64 * 65];          // padded: (lane+n)%32 -> 2-way (free)
    const int tid = threadIdx.x;
    const int wave = tid >> 6, lane = tid & 63;
    const int cpb = NCH >> 2;
    const int b   = blockIdx.x / (16 * cpb);
    const int rem = blockIdx.x % (16 * cpb);
    const int dt  = rem / cpb;
    const int jg  = rem % cpb;
    const int j   = (jg << 2) | wave;
    const int d   = (dt << 6) | lane;

    if (tid < NSTATE) {
        float A = -expf(A_log[tid]);
        r_lds[tid] = expf(delta[0] * A);
    }
    for (int k = tid; k < 64 * 64; k += 256) {
        int row = k >> 6, col = k & 63;
        c_lds[row * 65 + col] = C[(size_t)((dt << 6) + row) * NSTATE + col];
    }
    __syncthreads();

    float s[NSTATE];
    const float* Ib = I + (((size_t)b * NCH + j) * NSTATE) * DMODEL + d;
#pragma unroll
    for (int n = 0; n < NSTATE; ++n) s[n] = Ib[(size_t)n * DMODEL];

    const float Dd = Dvec[d];
    const float* ub = u + ((size_t)b * SEQL + (size_t)j * T) * DMODEL + d;
    float*       yb = y + ((size_t)b * SEQL + (size_t)j * T) * DMODEL + d;
    const int ntb = T / TB;
    for (int tb = 0; tb < ntb; ++tb) {
        float ur[TB], yr[TB];
#pragma unroll
        for (int t = 0; t < TB; ++t) {
            ur[t] = ub[(size_t)(tb * TB + t) * DMODEL];
            yr[t] = 0.f;
        }
#pragma unroll
        for (int n = 0; n < NSTATE; ++n) {
            const float rn = r_lds[n];
            const float cn = c_lds[lane * 65 + n];
            float sn = s[n];
#pragma unroll
            for (int t = 0; t < TB; ++t) {
                sn = fmaf(rn, sn, ur[t]);
                yr[t] = fmaf(cn, sn, yr[t]);
            }
            s[n] = sn;
        }
#pragma unroll
        for (int t = 0; t < TB; ++t)
            yb[(size_t)(tb * TB + t) * DMODEL] = fmaf(Dd, ur[t], yr[t]);
    }
}

// ---------------------------------------------------------------------------
// LN kernel: fuses the analytically-simplified second FFT stage
//   z = freq_align[d]*y + (t==0 ? reward[d] : 0)
// with LayerNorm over d. In-place on d_out. One block per (b,t) row.
// ---------------------------------------------------------------------------
__global__ __launch_bounds__(256) void k_ln(float* __restrict__ y,
                                            const float* __restrict__ gamma,
                                            const float* __restrict__ beta,
                                            const float* __restrict__ freq_align,
                                            const float* __restrict__ reward) {
    const int t = blockIdx.x & (SEQL - 1);
    const int tid = threadIdx.x;
    float4* row = (float4*)(y + (size_t)blockIdx.x * DMODEL);
    float4 v = row[tid];
    float4 fa = ((const float4*)freq_align)[tid];
    float4 z;
    z.x = fa.x * v.x; z.y = fa.y * v.y; z.z = fa.z * v.z; z.w = fa.w * v.w;
    if (t == 0) {
        float4 rw = ((const float4*)reward)[tid];
        z.x += rw.x; z.y += rw.y; z.z += rw.z; z.w += rw.w;
    }
    float sum = z.x + z.y + z.z + z.w;
    float sq  = z.x*z.x + z.y*z.y + z.z*z.z + z.w*z.w;
#pragma unroll
    for (int off = 32; off > 0; off >>= 1) {
        sum += __shfl_down(sum, off, 64);
        sq  += __shfl_down(sq,  off, 64);
    }
    __shared__ float red[8];
    const int wave = tid >> 6, lane = tid & 63;
    if (lane == 0) { red[wave] = sum; red[4 + wave] = sq; }
    __syncthreads();
    sum = red[0] + red[1] + red[2] + red[3];
    sq  = red[4] + red[5] + red[6] + red[7];
    const float mean = sum * (1.f / DMODEL);
    const float var  = sq * (1.f / DMODEL) - mean * mean;
    const float inv  = 1.f / sqrtf(var + LN_EPS);
    float4 g = ((const float4*)gamma)[tid];
    float4 bb = ((const float4*)beta)[tid];
    float4 o;
    o.x = (z.x - mean) * inv * g.x + bb.x;
    o.y = (z.y - mean) * inv * g.y + bb.y;
    o.z = (z.z - mean) * inv * g.z + bb.z;
    o.w = (z.w - mean) * inv * g.w + bb.w;
    row[tid] = o;
}

// ---------------------------------------------------------------------------
// Final state: final_state[b,n] = ((exp(dmean*A_n)-1)/A_safe_n) *
//                                 sum_d B[n,d] * u[b, L-1, d]
// ---------------------------------------------------------------------------
__global__ __launch_bounds__(256) void k_state(const float* __restrict__ u,
                                               const float* __restrict__ A_log,
                                               const float* __restrict__ B,
                                               const float* __restrict__ delta,
                                               float* __restrict__ out) {
    const int n = blockIdx.x & 63;
    const int b = blockIdx.x >> 6;
    const int tid = threadIdx.x;
    const float* ul = u + ((size_t)b * SEQL + (SEQL - 1)) * DMODEL;
    const float* Bn = B + (size_t)n * DMODEL;
    float dot = 0.f, dsum = 0.f;
    for (int dd = tid; dd < DMODEL; dd += 256) {
        dot = fmaf(Bn[dd], ul[dd], dot);
        dsum += delta[dd];
    }
#pragma unroll
    for (int off = 32; off > 0; off >>= 1) {
        dot  += __shfl_down(dot,  off, 64);
        dsum += __shfl_down(dsum, off, 64);
    }
    __shared__ float red[8];
    const int wave = tid >> 6, lane = tid & 63;
    if (lane == 0) { red[wave] = dot; red[4 + wave] = dsum; }
    __syncthreads();
    if (tid == 0) {
        dot  = red[0] + red[1] + red[2] + red[3];
        dsum = red[4] + red[5] + red[6] + red[7];
        const float dmean = dsum * (1.f / DMODEL);
        const float A = -expf(A_log[n]);
        const float Abar = expf(dmean * A);
        const float Asafe = A + (A >= 0.f ? 1e-8f : -1e-8f);
        out[blockIdx.x] = ((Abar - 1.f) / Asafe) * dot;
    }
}

extern "C" void kernel_launch(void* const* d_in, const int* in_sizes, int n_in,
                              void* d_out, int out_size, void* d_ws, size_t ws_size,
                              hipStream_t stream) {
    const float* u     = (const float*)d_in[0];
    const float* A_log = (const float*)d_in[1];
    const float* B     = (const float*)d_in[2];
    const float* C     = (const float*)d_in[3];
    const float* Dv    = (const float*)d_in[4];
    const float* delta = (const float*)d_in[5];
    const float* gamma = (const float*)d_in[6];
    const float* beta  = (const float*)d_in[7];
    const float* fal   = (const float*)d_in[8];
    const float* rw    = (const float*)d_in[9];

    float* y  = (float*)d_out;
    float* st = y + (size_t)BATCH * SEQL * DMODEL;
    float* f  = (float*)d_ws;

    // chunk count: prefer 32 (T=128, best occupancy); shrink if ws too small
    int NCH = 32;
    while (NCH > 4 && (size_t)BATCH * NCH * NSTATE * DMODEL * sizeof(float) > ws_size)
        NCH >>= 1;
    const int T = SEQL / NCH;

    const dim3 blk(256);
    const int nb13 = BATCH * (DMODEL / 64) * (NCH / 4);

    hipLaunchKernelGGL(k_pass1, dim3(nb13), blk, 0, stream, u, A_log, delta, f, NCH, T);
    hipLaunchKernelGGL(k_pass2, dim3(BATCH * NSTATE * DMODEL / 256), blk, 0, stream,
                       A_log, delta, f, NCH, T);
    hipLaunchKernelGGL(k_pass3, dim3(nb13), blk, 0, stream, u, A_log, C, Dv, delta,
                       f, y, NCH, T);
    hipLaunchKernelGGL(k_ln, dim3(BATCH * SEQL), blk, 0, stream, y, gamma, beta, fal, rw);
    hipLaunchKernelGGL(k_state, dim3(BATCH * NSTATE), blk, 0, stream, u, A_log, B, delta, st);
}